// Round 10
// baseline (24290.599 us; speedup 1.0000x reference)
//
#include <hip/hip_runtime.h>
#include <hip/hip_bf16.h>

#define TT 2048
#define HH 1024
#define GH 4096

__device__ __forceinline__ float sigm(float x){ return 1.0f / (1.0f + __expf(-x)); }

// -------- Phase 1: plain fp32 tiled GEMM (validated r3-r9) --------
#define BM 128
#define BN 64
#define BK 32

__global__ __launch_bounds__(256) void gemm_simple(
    const int* __restrict__ tokens,
    const float* __restrict__ emb,
    const float* __restrict__ Wih,
    const float* __restrict__ bih,
    const float* __restrict__ bhh,
    float* __restrict__ gx)
{
  __shared__ float As[BM][BK+1];
  __shared__ float Bs[BN][BK+1];
  __shared__ int tok_s[BM];

  const int tid = threadIdx.x;
  const int bn = blockIdx.x;
  const int bm = blockIdx.y;
  const int m0 = bm*BM, n0 = bn*BN;

  if (tid < BM) tok_s[tid] = tokens[m0 + tid];
  __syncthreads();

  const int tm = tid >> 4;
  const int tn = tid & 15;

  float acc[8][4];
  #pragma unroll
  for (int i = 0; i < 8; ++i)
    #pragma unroll
    for (int j = 0; j < 4; ++j) acc[i][j] = 0.0f;

  for (int k0 = 0; k0 < HH; k0 += BK) {
    for (int idx = tid; idx < BM*BK; idx += 256) {
      int r = idx >> 5, c = idx & 31;
      As[r][c] = emb[(size_t)tok_s[r]*HH + k0 + c];
    }
    for (int idx = tid; idx < BN*BK; idx += 256) {
      int r = idx >> 5, c = idx & 31;
      Bs[r][c] = Wih[(size_t)(n0 + r)*HH + k0 + c];
    }
    __syncthreads();
    #pragma unroll
    for (int k = 0; k < BK; ++k) {
      float a[8], bb[4];
      #pragma unroll
      for (int i = 0; i < 8; ++i) a[i] = As[tm*8 + i][k];
      #pragma unroll
      for (int j = 0; j < 4; ++j) bb[j] = Bs[tn*4 + j][k];
      #pragma unroll
      for (int i = 0; i < 8; ++i)
        #pragma unroll
        for (int j = 0; j < 4; ++j)
          acc[i][j] = fmaf(a[i], bb[j], acc[i][j]);
    }
    __syncthreads();
  }

  float bias[4];
  #pragma unroll
  for (int j = 0; j < 4; ++j) {
    int col = n0 + tn*4 + j;
    bias[j] = bih[col] + bhh[col];
  }
  #pragma unroll
  for (int i = 0; i < 8; ++i) {
    int r = m0 + tm*8 + i;
    #pragma unroll
    for (int j = 0; j < 4; ++j)
      gx[(size_t)r*GH + (n0 + tn*4 + j)] = acc[i][j] + bias[j];
  }
}

// -------- Phase 2: wave-autonomous scan, ONE output per wave --------
// 64 blocks x 16 waves; wave owns output o = b*16+wv. w[4][16]=64 floats/lane
// (fits 128-VGPR budget; no spill, no remat). Every wave polls all 1024 slots
// (coalesced lane+64j == its h vector). No LDS, no barriers.
// Safety: each wave reads every slot each step => publisher reaches tag t+2
// only after all waves consumed tag t => 2-parity ping-pong is race-free.
#define GBLK 64
#define NTH 1024

__global__ __launch_bounds__(NTH, 4) void lstm_scan(
    const float* __restrict__ gx,
    const float* __restrict__ Whh,
    unsigned long long* slots,     // [2][1024] {tag<<32 | fp32 h}
    float* __restrict__ out)       // [2048] fp32 = h ; c
{
  const int b    = blockIdx.x;
  const int tid  = threadIdx.x;
  const int lane = tid & 63;
  const int wv   = tid >> 6;          // 0..15
  const int o    = (b << 4) + wv;     // owned output index

  // w[g][j] = Whh[g*1024 + o][64*j + lane]
  float w[4][16];
  #pragma unroll
  for (int g = 0; g < 4; ++g) {
    const float* wr = Whh + (size_t)((g << 10) + o) * HH + lane;
    #pragma unroll
    for (int j = 0; j < 16; ++j) w[g][j] = wr[64 * j];
  }
  #pragma unroll
  for (int g = 0; g < 4; ++g)
    #pragma unroll
    for (int j = 0; j < 16; ++j)
      asm volatile("" : "+v"(w[g][j]));   // keep live; footprint now fits budget

  float cst = 0.0f;
  float g4[4];
  #pragma unroll
  for (int g = 0; g < 4; ++g) g4[g] = gx[(g << 10) + o];   // t=0 (broadcast load)

  float h[16];
  #pragma unroll
  for (int j = 0; j < 16; ++j) h[j] = 0.0f;                // h(0) = 0

  for (int t = 0; t < TT; ++t) {
    // prefetch next step's gx first: HBM latency hides under the poll
    float ng[4] = {0.f, 0.f, 0.f, 0.f};
    if (t + 1 < TT) {
      #pragma unroll
      for (int g = 0; g < 4; ++g)
        ng[g] = gx[(size_t)(t+1)*GH + (g << 10) + o];
    }

    if (t > 0) {
      const unsigned long long* sb = slots + (size_t)(t & 1) * 1024;
      const unsigned tg = (unsigned)t;
      unsigned long long v[16];
      #pragma unroll
      for (int j = 0; j < 16; ++j)      // issue all 16 in parallel
        v[j] = __hip_atomic_load(&sb[lane + 64*j], __ATOMIC_RELAXED, __HIP_MEMORY_SCOPE_AGENT);
      #pragma unroll
      for (int j = 0; j < 16; ++j)      // fix stragglers
        while ((unsigned)(v[j] >> 32) != tg)
          v[j] = __hip_atomic_load(&sb[lane + 64*j], __ATOMIC_RELAXED, __HIP_MEMORY_SCOPE_AGENT);
      #pragma unroll
      for (int j = 0; j < 16; ++j) h[j] = __uint_as_float((unsigned)v[j]);
    }

    float acc[4] = {0.f, 0.f, 0.f, 0.f};
    #pragma unroll
    for (int j = 0; j < 16; ++j) {
      const float hj = h[j];
      #pragma unroll
      for (int g = 0; g < 4; ++g) acc[g] = fmaf(w[g][j], hj, acc[g]);
    }

    // folded butterfly: lane l ends holding full sum of gate (l&3)
    float v2[2];
    #pragma unroll
    for (int i = 0; i < 2; ++i) {
      float a = (lane & 1) ? acc[2*i+1] : acc[2*i];
      float q = (lane & 1) ? acc[2*i]   : acc[2*i+1];
      v2[i] = a + __shfl_xor(q, 1);
    }
    float v1;
    {
      float a = (lane & 2) ? v2[1] : v2[0];
      float q = (lane & 2) ? v2[0] : v2[1];
      v1 = a + __shfl_xor(q, 2);
    }
    v1 += __shfl_xor(v1, 4);
    v1 += __shfl_xor(v1, 8);
    v1 += __shfl_xor(v1, 16);
    v1 += __shfl_xor(v1, 32);

    // all lanes gather the 4 gate sums (broadcast shfl), redundant activation
    float xi = __shfl(v1, 0) + g4[0];
    float xf = __shfl(v1, 1) + g4[1];
    float xg = __shfl(v1, 2) + g4[2];
    float xo = __shfl(v1, 3) + g4[3];

    cst = sigm(xf)*cst + sigm(xi)*tanhf(xg);
    float hnew = sigm(xo)*tanhf(cst);

    if (t == TT-1) {
      if (lane == 0) {
        out[o]        = hnew;
        out[1024 + o] = cst;
      }
    } else {
      if (lane == 0) {
        unsigned long long pv =
            (((unsigned long long)(unsigned)(t+1)) << 32) |
            (unsigned long long)__float_as_uint(hnew);
        __hip_atomic_store(&slots[(size_t)((t+1) & 1)*1024 + o], pv,
                           __ATOMIC_RELAXED, __HIP_MEMORY_SCOPE_AGENT);
      }
      #pragma unroll
      for (int g = 0; g < 4; ++g) g4[g] = ng[g];
    }
  }
}

// fallback: ws too small -> zeros
__global__ void zero_out(float* out){
  int i = blockIdx.x*256 + threadIdx.x;
  if (i < 2048) out[i] = 0.0f;
}

extern "C" void kernel_launch(void* const* d_in, const int* in_sizes, int n_in,
                              void* d_out, int out_size, void* d_ws, size_t ws_size,
                              hipStream_t stream) {
  (void)in_sizes; (void)n_in; (void)out_size;
  const int* tokens = (const int*)d_in[0];
  const float* emb  = (const float*)d_in[1];
  const float* Wih  = (const float*)d_in[2];
  const float* Whh  = (const float*)d_in[3];
  const float* bih  = (const float*)d_in[4];
  const float* bhh  = (const float*)d_in[5];
  float* out = (float*)d_out;

  // ws: [0,16K) slots[2][1024] u64 | [16K, ...) gx fp32 [2048][4096]
  unsigned long long* slots = (unsigned long long*)d_ws;
  float* gx = (float*)((char*)d_ws + 16384);
  const size_t needF32 = 16384 + (size_t)TT*GH*sizeof(float);

  hipMemsetAsync(slots, 0, 16384, stream);
  if (ws_size >= needF32) {
    gemm_simple<<<dim3(64,16), dim3(256), 0, stream>>>(tokens, emb, Wih, bih, bhh, gx);
    lstm_scan<<<dim3(GBLK), dim3(NTH), 0, stream>>>(gx, Whh, slots, out);
  } else {
    zero_out<<<dim3(8), dim3(256), 0, stream>>>(out);
  }
}

// Round 11
// 15567.036 us; speedup vs baseline: 1.5604x; 1.5604x over previous
//
#include <hip/hip_runtime.h>
#include <hip/hip_bf16.h>

#define TT 2048
#define HH 1024
#define GH 4096

__device__ __forceinline__ float sigm(float x){ return 1.0f / (1.0f + __expf(-x)); }

// -------- Phase 1: plain fp32 tiled GEMM (validated r3-r10) --------
#define BM 128
#define BN 64
#define BK 32

__global__ __launch_bounds__(256) void gemm_simple(
    const int* __restrict__ tokens,
    const float* __restrict__ emb,
    const float* __restrict__ Wih,
    const float* __restrict__ bih,
    const float* __restrict__ bhh,
    float* __restrict__ gx)
{
  __shared__ float As[BM][BK+1];
  __shared__ float Bs[BN][BK+1];
  __shared__ int tok_s[BM];

  const int tid = threadIdx.x;
  const int bn = blockIdx.x;
  const int bm = blockIdx.y;
  const int m0 = bm*BM, n0 = bn*BN;

  if (tid < BM) tok_s[tid] = tokens[m0 + tid];
  __syncthreads();

  const int tm = tid >> 4;
  const int tn = tid & 15;

  float acc[8][4];
  #pragma unroll
  for (int i = 0; i < 8; ++i)
    #pragma unroll
    for (int j = 0; j < 4; ++j) acc[i][j] = 0.0f;

  for (int k0 = 0; k0 < HH; k0 += BK) {
    for (int idx = tid; idx < BM*BK; idx += 256) {
      int r = idx >> 5, c = idx & 31;
      As[r][c] = emb[(size_t)tok_s[r]*HH + k0 + c];
    }
    for (int idx = tid; idx < BN*BK; idx += 256) {
      int r = idx >> 5, c = idx & 31;
      Bs[r][c] = Wih[(size_t)(n0 + r)*HH + k0 + c];
    }
    __syncthreads();
    #pragma unroll
    for (int k = 0; k < BK; ++k) {
      float a[8], bb[4];
      #pragma unroll
      for (int i = 0; i < 8; ++i) a[i] = As[tm*8 + i][k];
      #pragma unroll
      for (int j = 0; j < 4; ++j) bb[j] = Bs[tn*4 + j][k];
      #pragma unroll
      for (int i = 0; i < 8; ++i)
        #pragma unroll
        for (int j = 0; j < 4; ++j)
          acc[i][j] = fmaf(a[i], bb[j], acc[i][j]);
    }
    __syncthreads();
  }

  float bias[4];
  #pragma unroll
  for (int j = 0; j < 4; ++j) {
    int col = n0 + tn*4 + j;
    bias[j] = bih[col] + bhh[col];
  }
  #pragma unroll
  for (int i = 0; i < 8; ++i) {
    int r = m0 + tm*8 + i;
    #pragma unroll
    for (int j = 0; j < 4; ++j)
      gx[(size_t)r*GH + (n0 + tn*4 + j)] = acc[i][j] + bias[j];
  }
}

// -------- Phase 2: persistent scan, 128 blocks x (8 compute + 1 listener) waves --------
// Compute wave w owns output o=b*8+w: w[4][16]=64 wt floats/lane (total live ~110
// VGPR < 128 tier => allocator keeps in regs). Listener polls all 1024 slots
// (1 MB/step chip-wide) into LDS h double-buffer. One barrier/step.
// Ping-pong safety: publish(t+2) happens-after local listener consumed t+1
// (loads drained by the pre-barrier vmcnt); any t+3 overwrite happens-after
// ALL listeners consumed t+1. Race-free with 2 parities.
#define GBLK 128
#define NTH 576

__global__ __launch_bounds__(NTH) void lstm_scan(
    const float* __restrict__ gx,
    const float* __restrict__ Whh,
    unsigned long long* slots,     // [2][1024] {tag<<32 | fp32 h}
    float* __restrict__ out)       // [2048] fp32 = h ; c
{
  const int b    = blockIdx.x;
  const int tid  = threadIdx.x;
  const int lane = tid & 63;
  const int wv   = tid >> 6;          // 0..8
  const bool isListener = (wv == 8);
  const int o    = (b << 3) + wv;     // owned output (compute waves)

  __shared__ float hbuf[2][1024];

  // w[g][j] = Whh[g*1024 + o][64*j + lane]  (coalesced 256B loads)
  float w[4][16];
  if (!isListener) {
    #pragma unroll
    for (int g = 0; g < 4; ++g) {
      const float* wr = Whh + (size_t)((g << 10) + o) * HH + lane;
      #pragma unroll
      for (int j = 0; j < 16; ++j) w[g][j] = wr[64 * j];
    }
    #pragma unroll
    for (int g = 0; g < 4; ++g)
      #pragma unroll
      for (int j = 0; j < 16; ++j)
        asm volatile("" : "+v"(w[g][j]));   // forbid remat; fits 128-VGPR tier
  }

  float cst = 0.0f;
  float g4[4] = {0.f, 0.f, 0.f, 0.f};
  if (!isListener) {
    #pragma unroll
    for (int g = 0; g < 4; ++g) g4[g] = gx[(g << 10) + o];   // t=0 (broadcast)
  }

  for (int i = tid; i < 1024; i += NTH) hbuf[0][i] = 0.0f;   // h(0) = 0
  __syncthreads();

  for (int t = 0; t < TT; ++t) {
    const int cur = t & 1, nxt = cur ^ 1;

    if (isListener) {
      if (t < TT-1) {                  // collect h(t+1) into hbuf[nxt]
        const unsigned long long* sb = slots + (size_t)nxt * 1024;
        const unsigned tg = (unsigned)(t+1);
        unsigned long long v[16];
        #pragma unroll
        for (int j = 0; j < 16; ++j)
          v[j] = __hip_atomic_load(&sb[lane + 64*j], __ATOMIC_RELAXED, __HIP_MEMORY_SCOPE_AGENT);
        #pragma unroll
        for (int j = 0; j < 16; ++j)
          while ((unsigned)(v[j] >> 32) != tg)
            v[j] = __hip_atomic_load(&sb[lane + 64*j], __ATOMIC_RELAXED, __HIP_MEMORY_SCOPE_AGENT);
        #pragma unroll
        for (int j = 0; j < 16; ++j)
          hbuf[nxt][64*j + lane] = __uint_as_float((unsigned)v[j]);
      }
    } else {
      float ng[4] = {0.f, 0.f, 0.f, 0.f};
      if (t + 1 < TT) {
        #pragma unroll
        for (int g = 0; g < 4; ++g)      // prefetch next gx under this step
          ng[g] = gx[(size_t)(t+1)*GH + (g << 10) + o];
      }

      float h[16];
      #pragma unroll
      for (int j = 0; j < 16; ++j) h[j] = hbuf[cur][64*j + lane];  // 2-way bank = free

      float acc[4] = {0.f, 0.f, 0.f, 0.f};
      #pragma unroll
      for (int j = 0; j < 16; ++j) {
        const float hj = h[j];
        #pragma unroll
        for (int g = 0; g < 4; ++g) acc[g] = fmaf(w[g][j], hj, acc[g]);
      }

      // folded butterfly: lane l ends holding full sum of gate (l&3)
      float v2[2];
      #pragma unroll
      for (int i = 0; i < 2; ++i) {
        float a = (lane & 1) ? acc[2*i+1] : acc[2*i];
        float q = (lane & 1) ? acc[2*i]   : acc[2*i+1];
        v2[i] = a + __shfl_xor(q, 1);
      }
      float v1;
      {
        float a = (lane & 2) ? v2[1] : v2[0];
        float q = (lane & 2) ? v2[0] : v2[1];
        v1 = a + __shfl_xor(q, 2);
      }
      v1 += __shfl_xor(v1, 4);
      v1 += __shfl_xor(v1, 8);
      v1 += __shfl_xor(v1, 16);
      v1 += __shfl_xor(v1, 32);

      // every lane gathers all 4 gate sums; redundant activation (no divergence)
      float xi = __shfl(v1, 0) + g4[0];
      float xf = __shfl(v1, 1) + g4[1];
      float xg = __shfl(v1, 2) + g4[2];
      float xo = __shfl(v1, 3) + g4[3];

      cst = sigm(xf)*cst + sigm(xi)*tanhf(xg);
      float hnew = sigm(xo)*tanhf(cst);

      if (t == TT-1) {
        if (lane == 0) {
          out[o]        = hnew;
          out[1024 + o] = cst;
        }
      } else {
        if (lane == 0) {
          unsigned long long pv =
              (((unsigned long long)(unsigned)(t+1)) << 32) |
              (unsigned long long)__float_as_uint(hnew);
          __hip_atomic_store(&slots[(size_t)nxt*1024 + o], pv,
                             __ATOMIC_RELAXED, __HIP_MEMORY_SCOPE_AGENT);
        }
        #pragma unroll
        for (int g = 0; g < 4; ++g) g4[g] = ng[g];
      }
    }
    __syncthreads();
  }
}

// fallback: ws too small -> zeros
__global__ void zero_out(float* out){
  int i = blockIdx.x*256 + threadIdx.x;
  if (i < 2048) out[i] = 0.0f;
}

extern "C" void kernel_launch(void* const* d_in, const int* in_sizes, int n_in,
                              void* d_out, int out_size, void* d_ws, size_t ws_size,
                              hipStream_t stream) {
  (void)in_sizes; (void)n_in; (void)out_size;
  const int* tokens = (const int*)d_in[0];
  const float* emb  = (const float*)d_in[1];
  const float* Wih  = (const float*)d_in[2];
  const float* Whh  = (const float*)d_in[3];
  const float* bih  = (const float*)d_in[4];
  const float* bhh  = (const float*)d_in[5];
  float* out = (float*)d_out;

  // ws: [0,16K) slots[2][1024] u64 | [16K, ...) gx fp32 [2048][4096]
  unsigned long long* slots = (unsigned long long*)d_ws;
  float* gx = (float*)((char*)d_ws + 16384);
  const size_t needF32 = 16384 + (size_t)TT*GH*sizeof(float);

  hipMemsetAsync(slots, 0, 16384, stream);
  if (ws_size >= needF32) {
    gemm_simple<<<dim3(64,16), dim3(256), 0, stream>>>(tokens, emb, Wih, bih, bhh, gx);
    lstm_scan<<<dim3(GBLK), dim3(NTH), 0, stream>>>(gx, Whh, slots, out);
  } else {
    zero_out<<<dim3(8), dim3(256), 0, stream>>>(out);
  }
}